// Round 1
// baseline (2680.432 us; speedup 1.0000x reference)
//
#include <hip/hip_runtime.h>

// Problem constants
#define B_    4
#define T_    1024
#define E_    512
#define Hh    8
#define L_    4
#define V_    32000
#define HID_  100
#define HIDP  128
#define BT    4096   // B_*T_

typedef float f32x4 __attribute__((ext_vector_type(4)));
typedef short s16x8 __attribute__((ext_vector_type(8)));

__device__ __forceinline__ short f2bf(float f) {
  unsigned u = __float_as_uint(f);
  u += 0x7fff + ((u >> 16) & 1);   // RNE to bf16
  return (short)(u >> 16);
}

__device__ __forceinline__ s16x8 cvt8(float4 a, float4 b) {
  s16x8 s;
  s[0] = f2bf(a.x); s[1] = f2bf(a.y); s[2] = f2bf(a.z); s[3] = f2bf(a.w);
  s[4] = f2bf(b.x); s[5] = f2bf(b.y); s[6] = f2bf(b.z); s[7] = f2bf(b.w);
  return s;
}

// ---------------------------------------------------------------------------
// Generic bf16-MFMA GEMM: C[M,N] = op(A[M,K] x B) * scale (+bias) (+relu) (+C)
// TRANSB=false: B is (K,N) row-major.  TRANSB=true: B is (N,K) row-major (B^T).
// Batched over gridDim.z with z -> (bz = z/Hn, hz = z%Hn) pointer offsets.
// Block tile 64x64, K-step 32, 256 threads = 4 waves, each wave a 16-row stripe.
// ---------------------------------------------------------------------------
template<bool TRANSB, bool BIAS, bool RELU, bool RESID>
__global__ __launch_bounds__(256) void gemm_k(
    const float* __restrict__ A, const float* __restrict__ B,
    float* __restrict__ C, const float* __restrict__ bias,
    int M, int N, int K, int lda, int ldb, int ldc,
    long sAb, long sAh, long sBb, long sBh, long sCb, long sCh,
    int Hn, float scale)
{
  const int z  = blockIdx.z;
  const int bz = z / Hn, hz = z - bz * Hn;
  A += bz * sAb + hz * sAh;
  B += bz * sBb + hz * sBh;
  C += bz * sCb + hz * sCh;

  const int bm = blockIdx.y << 6;
  const int bn = blockIdx.x << 6;

  // +8 short pad per row: keeps 16B alignment for b128 ops, breaks bank aliasing
  __shared__ short As[64 * 40];
  __shared__ short Bs[64 * 40];

  const int tid  = threadIdx.x;
  const int lane = tid & 63, w = tid >> 6;
  const int quad = lane >> 4, l15 = lane & 15;

  f32x4 acc[4];
#pragma unroll
  for (int i = 0; i < 4; i++) acc[i] = (f32x4){0.f, 0.f, 0.f, 0.f};

  const int arow = tid >> 2;             // 0..63
  const int acg  = (tid & 3) << 3;       // 0,8,16,24
  const int bkk  = tid >> 3;             // 0..31
  const int bng  = (tid & 7) << 3;       // 0,8,..,56

  for (int k0 = 0; k0 < K; k0 += 32) {
    { // A tile: As[m][k] = bf16(A[bm+m][k0+k]), m-major rows of 32 k
      const float* ap = A + (long)(bm + arow) * lda + (k0 + acg);
      float4 u0 = *(const float4*)ap;
      float4 u1 = *(const float4*)(ap + 4);
      *(s16x8*)&As[arow * 40 + acg] = cvt8(u0, u1);
    }
    if (TRANSB) { // Bs[n][k] = bf16(B[bn+n][k0+k])  (B^T input, rows contiguous)
      const float* bp = B + (long)(bn + arow) * ldb + (k0 + acg);
      float4 u0 = *(const float4*)bp;
      float4 u1 = *(const float4*)(bp + 4);
      *(s16x8*)&Bs[arow * 40 + acg] = cvt8(u0, u1);
    } else {      // Bs[n][k] = bf16(B[k0+k][bn+n])  (transpose during LDS store)
      const float* bp = B + (long)(k0 + bkk) * ldb + (bn + bng);
      float4 u0 = *(const float4*)bp;
      float4 u1 = *(const float4*)(bp + 4);
      float vv[8] = {u0.x, u0.y, u0.z, u0.w, u1.x, u1.y, u1.z, u1.w};
#pragma unroll
      for (int j = 0; j < 8; j++) Bs[(bng + j) * 40 + bkk] = f2bf(vv[j]);
    }
    __syncthreads();

    s16x8 af = *(const s16x8*)&As[(w * 16 + l15) * 40 + (quad << 3)];
#pragma unroll
    for (int nt = 0; nt < 4; nt++) {
      s16x8 bf = *(const s16x8*)&Bs[(nt * 16 + l15) * 40 + (quad << 3)];
      acc[nt] = __builtin_amdgcn_mfma_f32_16x16x32_bf16(af, bf, acc[nt], 0, 0, 0);
    }
    __syncthreads();
  }

  // Epilogue. C/D layout: col = lane&15, row = quad*4 + reg  [verified m89/m91]
#pragma unroll
  for (int nt = 0; nt < 4; nt++) {
#pragma unroll
    for (int r = 0; r < 4; r++) {
      int gr = bm + w * 16 + quad * 4 + r;
      int gc = bn + nt * 16 + l15;
      long ci = (long)gr * ldc + gc;
      float val = acc[nt][r] * scale;
      if (BIAS)  val += bias[gc];
      if (RELU)  val = fmaxf(val, 0.f);
      if (RESID) val += C[ci];
      C[ci] = val;
    }
  }
}

// ---------------------------------------------------------------------------
// x[bt][e] = tok_emb[idx[bt]][e] + pos_emb[t][e]
// ---------------------------------------------------------------------------
__global__ __launch_bounds__(256) void embed_k(
    const int* __restrict__ idx, const float4* __restrict__ tok,
    const float4* __restrict__ pos, float4* __restrict__ x)
{
  int i = blockIdx.x * 256 + threadIdx.x;   // over BT * (E_/4) = 524288
  int bt = i >> 7, e4 = i & 127;
  int t = bt & (T_ - 1);
  int token = idx[bt];
  float4 a = tok[(long)token * 128 + e4];
  float4 p = pos[(long)t * 128 + e4];
  x[i] = make_float4(a.x + p.x, a.y + p.y, a.z + p.z, a.w + p.w);
}

// ---------------------------------------------------------------------------
// LayerNorm: one block per row of 512
// ---------------------------------------------------------------------------
__global__ __launch_bounds__(256) void ln_k(
    const float* __restrict__ x, const float* __restrict__ g,
    const float* __restrict__ b, float* __restrict__ out)
{
  int row = blockIdx.x;
  const float* xr = x + (long)row * E_;
  int tid = threadIdx.x;
  float v0 = xr[tid], v1 = xr[tid + 256];
  float s = v0 + v1, ss = v0 * v0 + v1 * v1;
#pragma unroll
  for (int off = 32; off; off >>= 1) {
    s  += __shfl_down(s, off);
    ss += __shfl_down(ss, off);
  }
  __shared__ float red[8];
  int w = tid >> 6, lane = tid & 63;
  if (lane == 0) { red[w] = s; red[w + 4] = ss; }
  __syncthreads();
  if (tid == 0) {
    float S  = red[0] + red[1] + red[2] + red[3];
    float SS = red[4] + red[5] + red[6] + red[7];
    float m  = S * (1.f / E_);
    float var = SS * (1.f / E_) - m * m;
    red[0] = m; red[1] = rsqrtf(var + 1e-5f);
  }
  __syncthreads();
  float m = red[0], r = red[1];
  float* orow = out + (long)row * E_;
  orow[tid]       = (v0 - m) * r * g[tid] + b[tid];
  orow[tid + 256] = (v1 - m) * r * g[tid + 256] + b[tid + 256];
}

// ---------------------------------------------------------------------------
// Causal softmax in place on (B*H*T) rows of length T. One wave per row.
// ---------------------------------------------------------------------------
__global__ __launch_bounds__(256) void softmax_k(float* __restrict__ S)
{
  int w = threadIdx.x >> 6, lane = threadIdx.x & 63;
  long rid = (long)blockIdx.x * 4 + w;           // < B_*Hh*T_
  float* row = S + rid * (long)T_;
  int t = (int)(rid & (T_ - 1));
  float e[16];
  float mx = -3.4e38f;
#pragma unroll
  for (int i = 0; i < 16; i++) {
    int j = lane + i * 64;
    float v = (j <= t) ? row[j] : -3.4e38f;
    e[i] = v;
    mx = fmaxf(mx, v);
  }
#pragma unroll
  for (int off = 32; off; off >>= 1) mx = fmaxf(mx, __shfl_xor(mx, off));
  float sum = 0.f;
#pragma unroll
  for (int i = 0; i < 16; i++) {
    int j = lane + i * 64;
    float v = (j <= t) ? __expf(e[i] - mx) : 0.f;
    e[i] = v; sum += v;
  }
#pragma unroll
  for (int off = 32; off; off >>= 1) sum += __shfl_xor(sum, off);
  float inv = 1.f / sum;
#pragma unroll
  for (int i = 0; i < 16; i++) row[lane + i * 64] = e[i] * inv;
}

// ---------------------------------------------------------------------------
// Pad MLP weights HID 100 -> 128 with zeros (d_ws is poisoned every call)
// ---------------------------------------------------------------------------
__global__ __launch_bounds__(256) void pad_w1(
    const float* __restrict__ W1, const float* __restrict__ b1,
    float* __restrict__ W1p, float* __restrict__ b1p)
{
  int i = blockIdx.x * 256 + threadIdx.x;   // L_*E_*HIDP = 262144
  int j = i & 127;
  int lk = i >> 7;                          // l*512 + k
  W1p[i] = (j < HID_) ? W1[lk * HID_ + j] : 0.f;
  if (i < L_ * HIDP) {
    int l = i >> 7;
    b1p[i] = (j < HID_) ? b1[l * HID_ + j] : 0.f;
  }
}

__global__ __launch_bounds__(256) void pad_w2(
    const float* __restrict__ W2, float* __restrict__ W2p)
{
  int i = blockIdx.x * 256 + threadIdx.x;   // L_*HIDP*E_ = 262144
  int n = i & 511;
  int lj = i >> 9;                          // l*128 + j
  int j = lj & 127;
  int l = lj >> 7;
  W2p[i] = (j < HID_) ? W2[((long)l * HID_ + j) * E_ + n] : 0.f;
}

// ---------------------------------------------------------------------------
extern "C" void kernel_launch(void* const* d_in, const int* in_sizes, int n_in,
                              void* d_out, int out_size, void* d_ws, size_t ws_size,
                              hipStream_t stream)
{
  const int*   idx  = (const int*)  d_in[0];
  const float* tok  = (const float*)d_in[1];
  const float* pos  = (const float*)d_in[2];
  const float* ln1g = (const float*)d_in[3];
  const float* ln1b = (const float*)d_in[4];
  const float* Wq   = (const float*)d_in[5];
  const float* Wk   = (const float*)d_in[6];
  const float* Wv   = (const float*)d_in[7];
  const float* Wo   = (const float*)d_in[8];
  const float* bo   = (const float*)d_in[9];
  const float* ln2g = (const float*)d_in[10];
  const float* ln2b = (const float*)d_in[11];
  const float* W1   = (const float*)d_in[12];
  const float* b1   = (const float*)d_in[13];
  const float* W2   = (const float*)d_in[14];
  const float* b2   = (const float*)d_in[15];
  const float* lnfg = (const float*)d_in[16];
  const float* lnfb = (const float*)d_in[17];
  const float* Wlm  = (const float*)d_in[18];

  float* out = (float*)d_out;
  float* ws  = (float*)d_ws;

  float* x   = ws;
  float* h   = x   + (long)BT * E_;
  float* q   = h   + (long)BT * E_;
  float* kk  = q   + (long)BT * E_;
  float* v   = kk  + (long)BT * E_;
  float* y   = v   + (long)BT * E_;
  float* h2  = y   + (long)BT * E_;
  float* W1p = h2  + (long)BT * HIDP;
  float* W2p = W1p + (long)L_ * E_ * HIDP;
  float* b1p = W2p + (long)L_ * HIDP * E_;

  float* attn0 = out + (long)BT * V_;      // logits first, then attn maps
  const long TT = (long)T_ * T_;
  const long SE = (long)T_ * E_;           // per-batch stride in activations

  pad_w1<<<dim3(L_ * E_ * HIDP / 256), dim3(256), 0, stream>>>(W1, b1, W1p, b1p);
  pad_w2<<<dim3(L_ * HIDP * E_ / 256), dim3(256), 0, stream>>>(W2, W2p);
  embed_k<<<dim3(BT * E_ / 4 / 256), dim3(256), 0, stream>>>(
      idx, (const float4*)tok, (const float4*)pos, (float4*)x);

  for (int l = 0; l < L_; l++) {
    float* attnL = attn0 + (long)l * B_ * Hh * TT;

    ln_k<<<dim3(BT), dim3(256), 0, stream>>>(x, ln1g + l * E_, ln1b + l * E_, h);

    // q/k/v = h @ W{q,k,v}[l]   (4096x512x512)
    gemm_k<false,false,false,false><<<dim3(8,64,1), dim3(256), 0, stream>>>(
        h, Wq + (long)l * E_ * E_, q, nullptr,
        BT, E_, E_, E_, E_, E_, 0,0,0,0,0,0, 1, 1.f);
    gemm_k<false,false,false,false><<<dim3(8,64,1), dim3(256), 0, stream>>>(
        h, Wk + (long)l * E_ * E_, kk, nullptr,
        BT, E_, E_, E_, E_, E_, 0,0,0,0,0,0, 1, 1.f);
    gemm_k<false,false,false,false><<<dim3(8,64,1), dim3(256), 0, stream>>>(
        h, Wv + (long)l * E_ * E_, v, nullptr,
        BT, E_, E_, E_, E_, E_, 0,0,0,0,0,0, 1, 1.f);

    // scores = (q @ k^T) * 1/8  into d_out attn region (raw, pre-softmax)
    gemm_k<true,false,false,false><<<dim3(16,16,32), dim3(256), 0, stream>>>(
        q, kk, attnL, nullptr,
        T_, T_, 64, E_, E_, T_,
        SE, 64, SE, 64, (long)Hh * TT, TT, Hh, 0.125f);

    // causal softmax in place (also zeroes the masked upper triangle)
    softmax_k<<<dim3(B_ * Hh * T_ / 4), dim3(256), 0, stream>>>(attnL);

    // y = attn @ v   (per b,h: 1024x64x1024)
    gemm_k<false,false,false,false><<<dim3(1,16,32), dim3(256), 0, stream>>>(
        attnL, v, y, nullptr,
        T_, 64, T_, T_, E_, E_,
        (long)Hh * TT, TT, SE, 64, SE, 64, Hh, 1.f);

    // x += y @ Wo[l] + bo[l]
    gemm_k<false,true,false,true><<<dim3(8,64,1), dim3(256), 0, stream>>>(
        y, Wo + (long)l * E_ * E_, x, bo + l * E_,
        BT, E_, E_, E_, E_, E_, 0,0,0,0,0,0, 1, 1.f);

    ln_k<<<dim3(BT), dim3(256), 0, stream>>>(x, ln2g + l * E_, ln2b + l * E_, h);

    // h2 = relu(h @ W1p[l] + b1p[l])   (4096x128x512, cols 100..127 are 0)
    gemm_k<false,true,true,false><<<dim3(2,64,1), dim3(256), 0, stream>>>(
        h, W1p + (long)l * E_ * HIDP, h2, b1p + l * HIDP,
        BT, HIDP, E_, E_, HIDP, HIDP, 0,0,0,0,0,0, 1, 1.f);

    // x += h2 @ W2p[l] + b2[l]   (K=128, pad rows multiply exact zeros)
    gemm_k<false,true,false,true><<<dim3(8,64,1), dim3(256), 0, stream>>>(
        h2, W2p + (long)l * HIDP * E_, x, b2 + l * E_,
        BT, E_, HIDP, HIDP, E_, E_, 0,0,0,0,0,0, 1, 1.f);
  }

  ln_k<<<dim3(BT), dim3(256), 0, stream>>>(x, lnfg, lnfb, h);

  // logits = h @ Wlm   (4096x32000x512)
  gemm_k<false,false,false,false><<<dim3(V_ / 64, 64, 1), dim3(256), 0, stream>>>(
      h, Wlm, out, nullptr,
      BT, V_, E_, E_, V_, V_, 0,0,0,0,0,0, 1, 1.f);
}